// Round 4
// baseline (322.303 us; speedup 1.0000x reference)
//
#include <hip/hip_runtime.h>
#include <hip/hip_fp16.h>

typedef _Float16 half_t;
typedef _Float16 f16x8 __attribute__((ext_vector_type(8)));
typedef _Float16 f16x4 __attribute__((ext_vector_type(4)));
typedef float f32x4 __attribute__((ext_vector_type(4)));

// problem constants
#define NB   16
#define CD   640
#define HWD  4096
#define TT   77
#define CTXD 768
#define NH   8
#define DH   80
#define DP   96   // padded d / padded T for the attention kernel

#define GLOAD16(gp, lp)                                                        \
  __builtin_amdgcn_global_load_lds(                                            \
      (const __attribute__((address_space(1))) void*)(gp),                     \
      (__attribute__((address_space(3))) void*)(lp), 16, 0, 0)

// XCD-locality swizzle: 5 n-blocks of one m-panel -> same XCD.
// grid = 2560 = 8 XCD * 320 slots; 512 panels (%8==0) -> bijective.
__device__ inline void xcd_panel_map(int j, int& panel, int& nblk) {
  const int xcd = j & 7, slot = j >> 3;
  panel = (slot / 5) * 8 + xcd;
  nblk = slot % 5;
}

// ---------------- merged weight transpose + f32->f16 convert ----------------
__global__ __launch_bounds__(256) void wtrans_kernel(
    const float* __restrict__ Wq, const float* __restrict__ Wk,
    const float* __restrict__ Wv, const float* __restrict__ Wo,
    half_t* __restrict__ WqT, half_t* __restrict__ WkT,
    half_t* __restrict__ WvT, half_t* __restrict__ WoT) {
  __shared__ half_t tile[64][72];
  const int z = blockIdx.z;
  const float* src = (z == 0) ? Wq : (z == 1) ? Wk : (z == 2) ? Wv : Wo;
  half_t* dst      = (z == 0) ? WqT : (z == 1) ? WkT : (z == 2) ? WvT : WoT;
  const int R = (z == 1 || z == 2) ? CTXD : CD;
  const int r0 = blockIdx.y * 64, c0 = blockIdx.x * 64;
  if (r0 >= R) return;
  const int t = threadIdx.x;
  const int rr = t >> 4, cc = (t & 15) * 4;
#pragma unroll
  for (int j = 0; j < 4; ++j) {
    const int r = rr + j * 16;
    float4 v = *reinterpret_cast<const float4*>(&src[(long)(r0 + r) * CD + c0 + cc]);
    tile[cc + 0][r] = (half_t)v.x;
    tile[cc + 1][r] = (half_t)v.y;
    tile[cc + 2][r] = (half_t)v.z;
    tile[cc + 3][r] = (half_t)v.w;
  }
  __syncthreads();
  const int cr = t >> 2, rc = (t & 3) * 16;
  half_t* dp = &dst[(long)(c0 + cr) * R + r0 + rc];
  *reinterpret_cast<int4*>(dp)     = *reinterpret_cast<const int4*>(&tile[cr][rc]);
  *reinterpret_cast<int4*>(dp + 8) = *reinterpret_cast<const int4*>(&tile[cr][rc + 8]);
}

// ---------------- K/V projection ----------------
__global__ __launch_bounds__(256) void kv_kernel(
    const float* __restrict__ ctx,
    const half_t* __restrict__ WkT, const half_t* __restrict__ WvT,
    const float* __restrict__ bk, const float* __restrict__ bv,
    half_t* __restrict__ k_ws, half_t* __restrict__ vT_ws) {
  __shared__ half_t C_sm[80][32];
  const int n0 = blockIdx.x * 64;
  const int b  = blockIdx.y;
  const int kv = blockIdx.z;
  const half_t* WT  = kv ? WvT : WkT;
  const float* bias = kv ? bv : bk;
  const int tid = threadIdx.x;
  const int wave = tid >> 6, lane = tid & 63, g = lane >> 4, ln = lane & 15;

  f32x4 acc[5];
#pragma unroll
  for (int i = 0; i < 5; ++i) acc[i] = (f32x4){0.f, 0.f, 0.f, 0.f};

  for (int k0 = 0; k0 < CTXD; k0 += 32) {
    if (k0) __syncthreads();
    for (int i = tid; i < 320; i += 256) {
      const int r = i >> 2, c8 = (i & 3) * 8;
      f16x8 hv = {0, 0, 0, 0, 0, 0, 0, 0};
      if (r < TT) {
        const float* cp = ctx + ((long)b * TT + r) * CTXD + k0 + c8;
        float4 c0v = *reinterpret_cast<const float4*>(cp);
        float4 c1v = *reinterpret_cast<const float4*>(cp + 4);
        hv[0] = (half_t)c0v.x; hv[1] = (half_t)c0v.y;
        hv[2] = (half_t)c0v.z; hv[3] = (half_t)c0v.w;
        hv[4] = (half_t)c1v.x; hv[5] = (half_t)c1v.y;
        hv[6] = (half_t)c1v.z; hv[7] = (half_t)c1v.w;
      }
      *reinterpret_cast<f16x8*>(&C_sm[r][c8]) = hv;
    }
    __syncthreads();
    f16x8 bfr = *reinterpret_cast<const f16x8*>(
        &WT[(long)(n0 + wave * 16 + ln) * CTXD + k0 + g * 8]);
#pragma unroll
    for (int mt = 0; mt < 5; ++mt) {
      f16x8 afr = *reinterpret_cast<const f16x8*>(&C_sm[mt * 16 + ln][g * 8]);
      acc[mt] = __builtin_amdgcn_mfma_f32_16x16x32_f16(afr, bfr, acc[mt], 0, 0, 0);
    }
  }

  const int n = n0 + wave * 16 + ln;
  const float bsv = bias[n];
  const int h = n / DH, dd = n % DH;
  if (kv == 0) {
#pragma unroll
    for (int mt = 0; mt < 5; ++mt)
#pragma unroll
      for (int r = 0; r < 4; ++r) {
        const int t = mt * 16 + g * 4 + r;
        k_ws[(((long)b * NH + h) * 80 + t) * DP + dd] = (half_t)(acc[mt][r] + bsv);
      }
  } else {
#pragma unroll
    for (int mt = 0; mt < 5; ++mt) {
      const int t0 = mt * 16 + g * 4;
      f16x4 v4;
#pragma unroll
      for (int r = 0; r < 4; ++r) v4[r] = (half_t)(acc[mt][r] + bsv);
      *reinterpret_cast<f16x4*>(&vT_ws[(((long)b * NH + h) * 80 + dd) * DP + t0]) = v4;
    }
  }
}

// ---------------- fused x-transpose + Q projection ----------------
// x (B,640,4096) f32 read DIRECTLY; per K-step a 128px x 32ch A-tile is
// loaded 2 steps ahead into registers (8 coalesced float2 per thread:
// pixels 2*pgg,2*pgg+1 x channels cgg*8..+7), converted to f16 and written
// as TWO ds_write_b128.
//
// Bank-conflict fix (round 4): round 3's 4px x 4ch b64 writes collided
// 16-way (2.3e7 conflict cycles). Now: row permutation phys(r) =
// (r>>1) + 64*(r&1), so thread (lane=pgg, wave=cgg) writes phys rows
// {pgg, pgg+64} at slot cgg^((pgg>>1)&3). Per instruction, addr mod 128 =
// (lane&1)*64 + slot*16 -> 8 distinct 16B positions x 8 lanes — the exact
// structure our pgemm b128 READS use, measured 0 conflicts.
// Read side applies the same permutation: A-slot = g ^ ((ln>>2)&3)
// (loop-invariant); B keeps its own swizzle g ^ ((ln>>1)&3).
// vmcnt ledger (8-item LOADA + 2-item LOADB): steady outstanding after
// issue = B(t+1)2 + A(t+2)8 + B(t+2)2 = 12 -> vmcnt(12) drains A(t+1);
// vmcnt(10)+lgkm(0) drains B(t+1) + our ds_writes before the barrier.
__global__ __launch_bounds__(256, 3) void qgemm_kernel(
    const float* __restrict__ x, const half_t* __restrict__ BT,
    const float* __restrict__ bias, half_t* __restrict__ outp) {
  __shared__ __align__(16) half_t A_sm[3][128 * 32];   // 24 KB
  __shared__ __align__(16) half_t B_sm[3][128 * 32];   // 24 KB
  const int tid = threadIdx.x;
  const int lane = tid & 63, wave = tid >> 6;   // wave 0..3
  const int g = lane >> 4, ln = lane & 15;
  const int wm = wave >> 1, wn = wave & 1;      // 2 x 2 wave grid

  int panel, nblk;
  xcd_panel_map(blockIdx.x, panel, nblk);
  const long m0 = (long)panel * 128;
  const int n0 = nblk * 128;
  const int b  = (int)(m0 >> 12);
  const int p0 = (int)(m0 & 4095);

  // A staging: thread owns pixels (2*pgg, 2*pgg+1), channels cgg*8..cgg*8+7
  const int pgg = tid & 63;    // == lane
  const int cgg = tid >> 6;    // == wave
  const float* xg = x + ((long)b * CD + cgg * 8) * HWD + p0 + pgg * 2;
  // phys rows pgg / pgg+64; phys slot = cgg ^ ((pgg>>1)&3)  (halfs offsets)
  const int wb0 = pgg * 32 + (cgg ^ ((pgg >> 1) & 3)) * 8;
  const int wb1 = wb0 + 64 * 32;

  // B staging (gload_lds): identical to ogemm
  const int srow = tid >> 2;
  const int sk8 = ((tid & 3) ^ ((tid >> 3) & 3)) * 8;
  const half_t* bg0 = BT + (long)(n0 + srow) * CD + sk8;
  const half_t* bg1 = bg0 + 64 * CD;

  // fragment-read slots (loop-invariant)
  const int rsA = (g ^ ((ln >> 2) & 3)) * 8;
  const int rsB = (g ^ ((ln >> 1) & 3)) * 8;
  // A phys-row base for this lane (halfs): perm(row)=row>>1 + 64*(row&1)
  const int arow = (wm * 32 + (ln >> 1) + 64 * (ln & 1)) * 32 + rsA;

  f32x4 acc[4][4];
#pragma unroll
  for (int i = 0; i < 4; ++i)
#pragma unroll
    for (int j = 0; j < 4; ++j) acc[i][j] = (f32x4){0.f, 0.f, 0.f, 0.f};

  float2 ra[8], rb[8];   // two register A-buffers (16 VGPR each)

#define LOADA(R, xp)                                                  \
  do {                                                                \
    _Pragma("unroll")                                                 \
    for (int cc = 0; cc < 8; ++cc)                                    \
      R[cc] = *reinterpret_cast<const float2*>((xp) + cc * HWD);      \
  } while (0)

#define LOADB(kt, buf)                                                \
  do {                                                                \
    GLOAD16(bg0 + (long)(kt) * 32, &B_sm[buf][wave * 512]);           \
    GLOAD16(bg1 + (long)(kt) * 32, &B_sm[buf][2048 + wave * 512]);    \
  } while (0)

  // convert + two b128 writes (conflict-free 8-position spread)
#define CVTW(R, buf)                                                  \
  do {                                                                \
    f16x8 w0_, w1_;                                                   \
    _Pragma("unroll")                                                 \
    for (int cc = 0; cc < 8; ++cc) {                                  \
      w0_[cc] = (half_t)R[cc].x;                                      \
      w1_[cc] = (half_t)R[cc].y;                                      \
    }                                                                 \
    *reinterpret_cast<f16x8*>(&A_sm[buf][wb0]) = w0_;                 \
    *reinterpret_cast<f16x8*>(&A_sm[buf][wb1]) = w1_;                 \
  } while (0)

#define COMPUTE(buf)                                                  \
  do {                                                                \
    __builtin_amdgcn_s_barrier();                                     \
    __builtin_amdgcn_sched_barrier(0);                                \
    f16x8 af[4], bf[4];                                               \
    _Pragma("unroll")                                                 \
    for (int mi = 0; mi < 4; ++mi)                                    \
      af[mi] = *reinterpret_cast<const f16x8*>(                       \
          &A_sm[buf][arow + mi * 256]);                               \
    _Pragma("unroll")                                                 \
    for (int ni = 0; ni < 4; ++ni)                                    \
      bf[ni] = *reinterpret_cast<const f16x8*>(                       \
          &B_sm[buf][(wn * 64 + ni * 16 + ln) * 32 + rsB]);           \
    __builtin_amdgcn_s_setprio(1);                                    \
    _Pragma("unroll")                                                 \
    for (int mi = 0; mi < 4; ++mi)                                    \
      _Pragma("unroll")                                               \
      for (int ni = 0; ni < 4; ++ni)                                  \
        acc[mi][ni] = __builtin_amdgcn_mfma_f32_16x16x32_f16(         \
            af[mi], bf[ni], acc[mi][ni], 0, 0, 0);                    \
    __builtin_amdgcn_s_setprio(0);                                    \
    __builtin_amdgcn_s_barrier();                                     \
  } while (0)

  // prologue: A(0)->ra, B(0); A(1)->rb, B(1); convert A(0) into buf 0
  LOADA(ra, xg);
  LOADB(0, 0);
  LOADA(rb, xg + 32 * HWD);
  LOADB(1, 1);
  asm volatile("s_waitcnt vmcnt(12)" ::: "memory");   // A(0) drained
  CVTW(ra, 0);

  // main loop: bodies 0..17 (full), parity-static register sets
  const float* xk = xg + 64 * HWD;   // A(k2+2) base
  for (int k2 = 0; k2 < 18; k2 += 2) {
    const int c0 = k2 % 3, c1 = (k2 + 1) % 3, c2 = (k2 + 2) % 3;
    // body(k2): convert A(k2+1) (rb), prefetch A(k2+2) -> ra
    LOADA(ra, xk);
    LOADB(k2 + 2, c2);
    asm volatile("s_waitcnt vmcnt(12)" ::: "memory");  // A(k2+1) drained
    CVTW(rb, c1);
    asm volatile("s_waitcnt vmcnt(10) lgkmcnt(0)" ::: "memory");
    COMPUTE(c0);
    // body(k2+1): convert A(k2+2) (ra), prefetch A(k2+3) -> rb
    LOADA(rb, xk + 32 * HWD);
    LOADB(k2 + 3, c0);
    asm volatile("s_waitcnt vmcnt(12)" ::: "memory");  // A(k2+2) drained
    CVTW(ra, c2);
    asm volatile("s_waitcnt vmcnt(10) lgkmcnt(0)" ::: "memory");
    COMPUTE(c1);
    xk += 64 * HWD;
  }
  // tail: convert A(19), drain, compute steps 18 and 19
  asm volatile("s_waitcnt vmcnt(2)" ::: "memory");   // A(19) drained
  CVTW(rb, 1);
  asm volatile("s_waitcnt vmcnt(0) lgkmcnt(0)" ::: "memory");
  COMPUTE(0);
  COMPUTE(1);

  // epilogue: q f16 row-major + bias (direct stores, known-good)
  half_t* O = outp;
#pragma unroll
  for (int ni = 0; ni < 4; ++ni) {
    const int n = n0 + wn * 64 + ni * 16 + ln;
    const float bvv = bias[n];
#pragma unroll
    for (int mi = 0; mi < 4; ++mi) {
      const long m = m0 + wm * 64 + mi * 16 + g * 4;
      f32x4 v = acc[mi][ni];
#pragma unroll
      for (int r = 0; r < 4; ++r)
        O[(m + r) * CD + n] = (half_t)(v[r] + bvv);
    }
  }
#undef LOADA
#undef LOADB
#undef CVTW
#undef COMPUTE
}

// ---------------- O-projection GEMM, 128x128 tile (unchanged) ----------------
// A (M,640) f16 row-major (attn), BT = WoT. out = f32 (B,640,4096) + bias.
__global__ __launch_bounds__(256, 3) void ogemm_kernel(
    const half_t* __restrict__ A, const half_t* __restrict__ BT,
    const float* __restrict__ bias, float* __restrict__ outp) {
  __shared__ __align__(16) half_t A_sm[3][128 * 32];   // 24 KB
  __shared__ __align__(16) half_t B_sm[3][128 * 32];   // 24 KB
  const int tid = threadIdx.x;
  const int lane = tid & 63, wave = tid >> 6;   // wave 0..3
  const int g = lane >> 4, ln = lane & 15;
  const int wm = wave >> 1, wn = wave & 1;      // 2 x 2 wave grid

  int panel, nblk;
  xcd_panel_map(blockIdx.x, panel, nblk);
  const long m0 = (long)panel * 128;
  const int n0 = nblk * 128;

  const int srow = tid >> 2;                                  // 0..63
  const int sk8 = ((tid & 3) ^ ((tid >> 3) & 3)) * 8;
  const half_t* ag0 = A + (m0 + srow) * CD + sk8;
  const half_t* ag1 = ag0 + 64 * CD;                          // rows 64..127
  const half_t* bg0 = BT + (long)(n0 + srow) * CD + sk8;
  const half_t* bg1 = bg0 + 64 * CD;

  const int rs8 = (g ^ ((ln >> 1) & 3)) * 8;

  f32x4 acc[4][4];
#pragma unroll
  for (int i = 0; i < 4; ++i)
#pragma unroll
    for (int j = 0; j < 4; ++j) acc[i][j] = (f32x4){0.f, 0.f, 0.f, 0.f};

#define STAGE_AB(buf, kt)                                              \
  do {                                                                 \
    GLOAD16(ag0 + (long)(kt) * 32, &A_sm[buf][wave * 512]);            \
    GLOAD16(ag1 + (long)(kt) * 32, &A_sm[buf][2048 + wave * 512]);     \
    GLOAD16(bg0 + (long)(kt) * 32, &B_sm[buf][wave * 512]);            \
    GLOAD16(bg1 + (long)(kt) * 32, &B_sm[buf][2048 + wave * 512]);     \
  } while (0)

  STAGE_AB(0, 0);   // stage(0)
  STAGE_AB(1, 1);   // stage(1) -- 8 loads in flight

  const int nk = CD / 32;  // 20
  for (int kt = 0; kt < nk; ++kt) {
    const int cur = kt % 3;
    if (kt + 2 < nk) {
      STAGE_AB((kt + 2) % 3, kt + 2);
      asm volatile("s_waitcnt vmcnt(8)" ::: "memory");   // stage(t) done
    } else if (kt + 1 < nk) {
      asm volatile("s_waitcnt vmcnt(4)" ::: "memory");
    } else {
      asm volatile("s_waitcnt vmcnt(0)" ::: "memory");
    }
    __builtin_amdgcn_s_barrier();          // all waves' stage(t) confirmed
    __builtin_amdgcn_sched_barrier(0);     // no hoisting across the barrier
    f16x8 af[4], bf[4];
#pragma unroll
    for (int mi = 0; mi < 4; ++mi)
      af[mi] = *reinterpret_cast<const f16x8*>(
          &A_sm[cur][(wm * 64 + mi * 16 + ln) * 32 + rs8]);
#pragma unroll
    for (int ni = 0; ni < 4; ++ni)
      bf[ni] = *reinterpret_cast<const f16x8*>(
          &B_sm[cur][(wn * 64 + ni * 16 + ln) * 32 + rs8]);
    __builtin_amdgcn_s_setprio(1);
#pragma unroll
    for (int mi = 0; mi < 4; ++mi)
#pragma unroll
      for (int ni = 0; ni < 4; ++ni)
        acc[mi][ni] = __builtin_amdgcn_mfma_f32_16x16x32_f16(af[mi], bf[ni], acc[mi][ni], 0, 0, 0);
    __builtin_amdgcn_s_setprio(0);
    __builtin_amdgcn_s_barrier();          // buf[cur] free for reuse
  }

  float* O = outp;
#pragma unroll
  for (int mi = 0; mi < 4; ++mi) {
    const long m = m0 + wm * 64 + mi * 16 + g * 4;
    const long bb = m >> 12;
    const int p = (int)(m & 4095);
#pragma unroll
    for (int ni = 0; ni < 4; ++ni) {
      const int n = n0 + wn * 64 + ni * 16 + ln;
      const float bvv = bias[n];
      f32x4 v = acc[mi][ni];
      float4 o4 = make_float4(v[0] + bvv, v[1] + bvv, v[2] + bvv, v[3] + bvv);
      *reinterpret_cast<float4*>(&O[((bb * CD + n) << 12) + p]) = o4;
    }
  }
#undef STAGE_AB
}

// ---------------- fused attention (128 px / block, 512 threads) -------------
__global__ __launch_bounds__(512) void attn_kernel(
    const half_t* __restrict__ q_ws, const half_t* __restrict__ k_ws,
    const half_t* __restrict__ vT_ws, half_t* __restrict__ attn_ws) {
  __shared__ half_t K_sm[80][DP];
  __shared__ half_t V_sm[80][DP];
  __shared__ half_t Q_sm[128][DP];  // becomes P after softmax (pads stay 0)
  const int p0 = blockIdx.x * 128;
  const int h  = blockIdx.y;
  const int b  = blockIdx.z;
  const int tid = threadIdx.x, wave = tid >> 6, lane = tid & 63;
  const int g = lane >> 4, ln = lane & 15;

  const half_t* kp = k_ws  + ((long)b * NH + h) * 80 * DP;
  const half_t* vp = vT_ws + ((long)b * NH + h) * 80 * DP;
  for (int i = tid; i < 960; i += 512) {   // 80*96/8 int4 chunks
    reinterpret_cast<int4*>(K_sm)[i] = reinterpret_cast<const int4*>(kp)[i];
    reinterpret_cast<int4*>(V_sm)[i] = reinterpret_cast<const int4*>(vp)[i];
  }
  for (int i = tid; i < 1536; i += 512) {  // 128 rows x 12 chunks
    const int r = i / 12, c8 = i % 12;
    int4 v = make_int4(0, 0, 0, 0);
    if (c8 < 10)
      v = *reinterpret_cast<const int4*>(
          q_ws + ((long)(b * HWD + p0 + r)) * CD + h * DH + c8 * 8);
    *reinterpret_cast<int4*>(&Q_sm[r][c8 * 8]) = v;
  }
  __syncthreads();

  // S^T = K(80x96) @ Q^T(96x16)
  f32x4 s[5];
#pragma unroll
  for (int i = 0; i < 5; ++i) s[i] = (f32x4){0.f, 0.f, 0.f, 0.f};
#pragma unroll
  for (int ks = 0; ks < 3; ++ks) {
    f16x8 bq = *reinterpret_cast<const f16x8*>(&Q_sm[wave * 16 + ln][ks * 32 + g * 8]);
#pragma unroll
    for (int mt = 0; mt < 5; ++mt) {
      f16x8 ak = *reinterpret_cast<const f16x8*>(&K_sm[mt * 16 + ln][ks * 32 + g * 8]);
      s[mt] = __builtin_amdgcn_mfma_f32_16x16x32_f16(ak, bq, s[mt], 0, 0, 0);
    }
  }

  // masked softmax over t (valid t<77)
  const float sc = 0.11180339887498949f;   // 80^-0.5
  float mx = -1e30f;
#pragma unroll
  for (int mt = 0; mt < 5; ++mt)
#pragma unroll
    for (int r = 0; r < 4; ++r) {
      const int t = mt * 16 + g * 4 + r;
      const float v = s[mt][r] * sc;
      s[mt][r] = v;
      if (t < TT) mx = fmaxf(mx, v);
    }
  mx = fmaxf(mx, __shfl_xor(mx, 16));
  mx = fmaxf(mx, __shfl_xor(mx, 32));
  float e[5][4];
  float sum = 0.f;
#pragma unroll
  for (int mt = 0; mt < 5; ++mt)
#pragma unroll
    for (int r = 0; r < 4; ++r) {
      const int t = mt * 16 + g * 4 + r;
      float ev = 0.f;
      if (t < TT) { ev = __expf(s[mt][r] - mx); sum += ev; }
      e[mt][r] = ev;
    }
  sum += __shfl_xor(sum, 16);
  sum += __shfl_xor(sum, 32);
  const float inv = 1.f / sum;
#pragma unroll
  for (int mt = 0; mt < 5; ++mt) {
    f16x4 pv;
#pragma unroll
    for (int r = 0; r < 4; ++r) pv[r] = (half_t)(e[mt][r] * inv);
    *reinterpret_cast<f16x4*>(&Q_sm[wave * 16 + ln][mt * 16 + g * 4]) = pv;
  }

  // O^T = V^T(80x96) @ P(96x16)
  f32x4 o[5];
#pragma unroll
  for (int i = 0; i < 5; ++i) o[i] = (f32x4){0.f, 0.f, 0.f, 0.f};
#pragma unroll
  for (int ks = 0; ks < 3; ++ks) {
    f16x8 bp = *reinterpret_cast<const f16x8*>(&Q_sm[wave * 16 + ln][ks * 32 + g * 8]);
#pragma unroll
    for (int mt = 0; mt < 5; ++mt) {
      f16x8 av = *reinterpret_cast<const f16x8*>(&V_sm[mt * 16 + ln][ks * 32 + g * 8]);
      o[mt] = __builtin_amdgcn_mfma_f32_16x16x32_f16(av, bp, o[mt], 0, 0, 0);
    }
  }

  half_t* op = attn_ws + ((long)(b * HWD + p0 + wave * 16 + ln)) * CD + h * DH;
#pragma unroll
  for (int mt = 0; mt < 5; ++mt) {
    f16x4 v4;
#pragma unroll
    for (int r = 0; r < 4; ++r) v4[r] = (half_t)o[mt][r];
    *reinterpret_cast<f16x4*>(&op[mt * 16 + g * 4]) = v4;
  }
}

// ---------------- launch ----------------
extern "C" void kernel_launch(void* const* d_in, const int* in_sizes, int n_in,
                              void* d_out, int out_size, void* d_ws, size_t ws_size,
                              hipStream_t stream) {
  const float* x   = (const float*)d_in[0];
  const float* ctx = (const float*)d_in[1];
  const float* Wq  = (const float*)d_in[2];
  const float* bq  = (const float*)d_in[3];
  const float* Wk  = (const float*)d_in[4];
  const float* bk  = (const float*)d_in[5];
  const float* Wv  = (const float*)d_in[6];
  const float* bv  = (const float*)d_in[7];
  const float* Wo  = (const float*)d_in[8];
  const float* bo  = (const float*)d_in[9];
  float* out = (float*)d_out;

  char* ws = (char*)d_ws;
  size_t off = 0;
  auto alloc = [&](size_t bytes) {
    void* p = ws + off;
    off += (bytes + 255) & ~(size_t)255;
    return p;
  };
  half_t* WqT  = (half_t*)alloc((size_t)CD * CD * 2);
  half_t* WkT  = (half_t*)alloc((size_t)CD * CTXD * 2);
  half_t* WvT  = (half_t*)alloc((size_t)CD * CTXD * 2);
  half_t* WoT  = (half_t*)alloc((size_t)CD * CD * 2);
  half_t* kws  = (half_t*)alloc((size_t)NB * NH * 80 * DP * 2);
  half_t* vTws = (half_t*)alloc((size_t)NB * NH * 80 * DP * 2);
  half_t* q    = (half_t*)alloc((size_t)NB * HWD * CD * 2);
  half_t* attn = (half_t*)alloc((size_t)NB * HWD * CD * 2);

  // zero padded K / V^T (contiguous pair)
  hipMemsetAsync(kws, 0, (size_t)2 * NB * NH * 80 * DP * 2, stream);

  // weight transposes (f32 -> f16)
  wtrans_kernel<<<dim3(CD / 64, CTXD / 64, 4), 256, 0, stream>>>(
      Wq, Wk, Wv, Wo, WqT, WkT, WvT, WoT);

  // K/V projection
  kv_kernel<<<dim3(CD / 64, NB, 2), 256, 0, stream>>>(ctx, WkT, WvT, bk, bv, kws, vTws);

  // fused x-transpose + Q projection (reads x directly)
  qgemm_kernel<<<(CD / 128) * ((NB * HWD) / 128), 256, 0, stream>>>(
      x, WqT, bq, q);

  // fused attention (128 px / block)
  attn_kernel<<<dim3(HWD / 128, NH, NB), 512, 0, stream>>>(q, kws, vTws, attn);

  // O projection (128x128 tiles, triple-buffer 2-ahead + swizzle)
  ogemm_kernel<<<(CD / 128) * ((NB * HWD) / 128), 256, 0, stream>>>(
      attn, WoT, bo, out);
}

// Round 5
// 311.126 us; speedup vs baseline: 1.0359x; 1.0359x over previous
//
#include <hip/hip_runtime.h>
#include <hip/hip_fp16.h>

typedef _Float16 half_t;
typedef _Float16 f16x8 __attribute__((ext_vector_type(8)));
typedef _Float16 f16x4 __attribute__((ext_vector_type(4)));
typedef float f32x4 __attribute__((ext_vector_type(4)));

// problem constants
#define NB   16
#define CD   640
#define HWD  4096
#define TT   77
#define CTXD 768
#define NH   8
#define DH   80
#define DP   96   // padded d / padded T for the attention kernel

#define GLOAD16(gp, lp)                                                        \
  __builtin_amdgcn_global_load_lds(                                            \
      (const __attribute__((address_space(1))) void*)(gp),                     \
      (__attribute__((address_space(3))) void*)(lp), 16, 0, 0)

// XCD-locality swizzle: 5 n-blocks of one 256-row m-panel -> same XCD.
// grid = 1280 = 8 XCD * 160 slots; 256 panels (%8==0) -> bijective.
__device__ inline void xcd_panel_map(int j, int& panel, int& nblk) {
  const int xcd = j & 7, slot = j >> 3;
  panel = (slot / 5) * 8 + xcd;
  nblk = slot % 5;
}

// ---------------- x transpose + f32->f16 convert ----------------
// x (B, 640, 4096) f32 -> xt (B, 4096, 640) f16
__global__ __launch_bounds__(256) void xpose_kernel(
    const float* __restrict__ x, half_t* __restrict__ xt) {
  __shared__ half_t tile[64][72];
  const float* s = x + (long)blockIdx.z * CD * HWD;
  half_t* d = xt + (long)blockIdx.z * HWD * CD;
  const int r0 = blockIdx.y * 64;   // channel
  const int c0 = blockIdx.x * 64;   // pixel
  const int t = threadIdx.x;
  const int rr = t >> 4, cc = (t & 15) * 4;
#pragma unroll
  for (int j = 0; j < 4; ++j) {
    const int r = rr + j * 16;
    float4 v = *reinterpret_cast<const float4*>(&s[(long)(r0 + r) * HWD + c0 + cc]);
    tile[cc + 0][r] = (half_t)v.x;
    tile[cc + 1][r] = (half_t)v.y;
    tile[cc + 2][r] = (half_t)v.z;
    tile[cc + 3][r] = (half_t)v.w;
  }
  __syncthreads();
  const int cr = t >> 2, rc = (t & 3) * 16;
  half_t* dp = &d[(long)(c0 + cr) * CD + r0 + rc];
  *reinterpret_cast<int4*>(dp)     = *reinterpret_cast<const int4*>(&tile[cr][rc]);
  *reinterpret_cast<int4*>(dp + 8) = *reinterpret_cast<const int4*>(&tile[cr][rc + 8]);
}

// ---------------- merged weight transpose + f32->f16 convert ----------------
__global__ __launch_bounds__(256) void wtrans_kernel(
    const float* __restrict__ Wq, const float* __restrict__ Wk,
    const float* __restrict__ Wv, const float* __restrict__ Wo,
    half_t* __restrict__ WqT, half_t* __restrict__ WkT,
    half_t* __restrict__ WvT, half_t* __restrict__ WoT) {
  __shared__ half_t tile[64][72];
  const int z = blockIdx.z;
  const float* src = (z == 0) ? Wq : (z == 1) ? Wk : (z == 2) ? Wv : Wo;
  half_t* dst      = (z == 0) ? WqT : (z == 1) ? WkT : (z == 2) ? WvT : WoT;
  const int R = (z == 1 || z == 2) ? CTXD : CD;
  const int r0 = blockIdx.y * 64, c0 = blockIdx.x * 64;
  if (r0 >= R) return;
  const int t = threadIdx.x;
  const int rr = t >> 4, cc = (t & 15) * 4;
#pragma unroll
  for (int j = 0; j < 4; ++j) {
    const int r = rr + j * 16;
    float4 v = *reinterpret_cast<const float4*>(&src[(long)(r0 + r) * CD + c0 + cc]);
    tile[cc + 0][r] = (half_t)v.x;
    tile[cc + 1][r] = (half_t)v.y;
    tile[cc + 2][r] = (half_t)v.z;
    tile[cc + 3][r] = (half_t)v.w;
  }
  __syncthreads();
  const int cr = t >> 2, rc = (t & 3) * 16;
  half_t* dp = &dst[(long)(c0 + cr) * R + r0 + rc];
  *reinterpret_cast<int4*>(dp)     = *reinterpret_cast<const int4*>(&tile[cr][rc]);
  *reinterpret_cast<int4*>(dp + 8) = *reinterpret_cast<const int4*>(&tile[cr][rc + 8]);
}

// ---------------- K/V projection ----------------
__global__ __launch_bounds__(256) void kv_kernel(
    const float* __restrict__ ctx,
    const half_t* __restrict__ WkT, const half_t* __restrict__ WvT,
    const float* __restrict__ bk, const float* __restrict__ bv,
    half_t* __restrict__ k_ws, half_t* __restrict__ vT_ws) {
  __shared__ half_t C_sm[80][32];
  const int n0 = blockIdx.x * 64;
  const int b  = blockIdx.y;
  const int kv = blockIdx.z;
  const half_t* WT  = kv ? WvT : WkT;
  const float* bias = kv ? bv : bk;
  const int tid = threadIdx.x;
  const int wave = tid >> 6, lane = tid & 63, g = lane >> 4, ln = lane & 15;

  f32x4 acc[5];
#pragma unroll
  for (int i = 0; i < 5; ++i) acc[i] = (f32x4){0.f, 0.f, 0.f, 0.f};

  for (int k0 = 0; k0 < CTXD; k0 += 32) {
    if (k0) __syncthreads();
    for (int i = tid; i < 320; i += 256) {
      const int r = i >> 2, c8 = (i & 3) * 8;
      f16x8 hv = {0, 0, 0, 0, 0, 0, 0, 0};
      if (r < TT) {
        const float* cp = ctx + ((long)b * TT + r) * CTXD + k0 + c8;
        float4 c0v = *reinterpret_cast<const float4*>(cp);
        float4 c1v = *reinterpret_cast<const float4*>(cp + 4);
        hv[0] = (half_t)c0v.x; hv[1] = (half_t)c0v.y;
        hv[2] = (half_t)c0v.z; hv[3] = (half_t)c0v.w;
        hv[4] = (half_t)c1v.x; hv[5] = (half_t)c1v.y;
        hv[6] = (half_t)c1v.z; hv[7] = (half_t)c1v.w;
      }
      *reinterpret_cast<f16x8*>(&C_sm[r][c8]) = hv;
    }
    __syncthreads();
    f16x8 bfr = *reinterpret_cast<const f16x8*>(
        &WT[(long)(n0 + wave * 16 + ln) * CTXD + k0 + g * 8]);
#pragma unroll
    for (int mt = 0; mt < 5; ++mt) {
      f16x8 afr = *reinterpret_cast<const f16x8*>(&C_sm[mt * 16 + ln][g * 8]);
      acc[mt] = __builtin_amdgcn_mfma_f32_16x16x32_f16(afr, bfr, acc[mt], 0, 0, 0);
    }
  }

  const int n = n0 + wave * 16 + ln;
  const float bsv = bias[n];
  const int h = n / DH, dd = n % DH;
  if (kv == 0) {
#pragma unroll
    for (int mt = 0; mt < 5; ++mt)
#pragma unroll
      for (int r = 0; r < 4; ++r) {
        const int t = mt * 16 + g * 4 + r;
        k_ws[(((long)b * NH + h) * 80 + t) * DP + dd] = (half_t)(acc[mt][r] + bsv);
      }
  } else {
#pragma unroll
    for (int mt = 0; mt < 5; ++mt) {
      const int t0 = mt * 16 + g * 4;
      f16x4 v4;
#pragma unroll
      for (int r = 0; r < 4; ++r) v4[r] = (half_t)(acc[mt][r] + bsv);
      *reinterpret_cast<f16x4*>(&vT_ws[(((long)b * NH + h) * 80 + dd) * DP + t0]) = v4;
    }
  }
}

// ---------------- panel GEMM, 256x128 tile, PHASE-SPLIT schedule ------------
// Round-0's proven 256x128 / 512-thread / 8-wave kernel (identical staging
// map, T2 swizzle, fragment reads, epilogues) with ONLY the K-loop schedule
// changed: each BK=32 step runs as 2 phases of 8 MFMA (T3), each phase =
// {ds_read subtile || issue stage loads -> barrier -> lgkmcnt(0)+
//  sched_barrier(0) -> setprio(1) MFMA x8 setprio(0) -> barrier},
// with ONE counted vmcnt(3) per step at phase 2 (T4): stage(t+1) drained,
// stage(t+2)'s 3 loads stay in flight across the barrier. Triple buffer.
// vmcnt ledger (3 loads/stage-set/wave, in order): after phase-2 issue,
// outstanding = [A(t+1)x2, B(t+1), A(t+2)x2, B(t+2)] = 6 -> vmcnt(3)
// retires exactly stage(t+1). Tail: t=18 vmcnt(0); t=19 no waits.
// Buffer-reuse fence: stage(t+2) writes buf[(t+2)%3] last read in step t-1
// phase 2, whose closing barrier precedes step t phase 1's issues.
template <int EPI>
__global__ __launch_bounds__(512, 4) void pgemm8_kernel(
    const half_t* __restrict__ A, const half_t* __restrict__ BT,
    const float* __restrict__ bias, void* __restrict__ outp) {
  __shared__ __align__(16) half_t A_sm[3][256 * 32];   // 48 KB
  __shared__ __align__(16) half_t B_sm[3][128 * 32];   // 24 KB
  const int tid = threadIdx.x;
  const int lane = tid & 63, wave = tid >> 6;   // wave 0..7
  const int g = lane >> 4, ln = lane & 15;
  const int wm = wave >> 1, wn = wave & 1;      // 4 x 2 wave grid

  int panel, nblk;
  xcd_panel_map(blockIdx.x, panel, nblk);
  const long m0 = (long)panel * 256;
  const int n0 = nblk * 128;

  // staging: lane l -> row wave*16+(l>>2), phys slot l&3 holds source
  // k-chunk (l&3)^((l>>3)&3)  [proven 0-conflict, rounds 0-4]
  const int srow = tid >> 2;                                  // 0..127
  const int sk8 = ((tid & 3) ^ ((tid >> 3) & 3)) * 8;
  const half_t* ag0 = A + (m0 + srow) * CD + sk8;
  const half_t* ag1 = ag0 + 128 * CD;                         // rows 128..255
  const half_t* bg0 = BT + (long)(n0 + srow) * CD + sk8;

  // fragment-read slot (loop-invariant): g ^ ((ln>>1)&3)
  const int rs8 = (g ^ ((ln >> 1) & 3)) * 8;

  f32x4 acc[4][4];
#pragma unroll
  for (int i = 0; i < 4; ++i)
#pragma unroll
    for (int j = 0; j < 4; ++j) acc[i][j] = (f32x4){0.f, 0.f, 0.f, 0.f};

#define STAGE_A(buf, kt)                                              \
  do {                                                                \
    GLOAD16(ag0 + (long)(kt) * 32, &A_sm[buf][wave * 512]);           \
    GLOAD16(ag1 + (long)(kt) * 32, &A_sm[buf][4096 + wave * 512]);    \
  } while (0)
#define STAGE_B(buf, kt)                                              \
  GLOAD16(bg0 + (long)(kt) * 32, &B_sm[buf][wave * 512])

#define READ_A2(dst0, dst1, buf, mi0)                                 \
  do {                                                                \
    dst0 = *reinterpret_cast<const f16x8*>(                           \
        &A_sm[buf][(wm * 64 + (mi0) * 16 + ln) * 32 + rs8]);          \
    dst1 = *reinterpret_cast<const f16x8*>(                           \
        &A_sm[buf][(wm * 64 + ((mi0) + 1) * 16 + ln) * 32 + rs8]);    \
  } while (0)
#define READ_B4(bf, buf)                                              \
  do {                                                                \
    _Pragma("unroll")                                                 \
    for (int ni = 0; ni < 4; ++ni)                                    \
      bf[ni] = *reinterpret_cast<const f16x8*>(                       \
          &B_sm[buf][(wn * 64 + ni * 16 + ln) * 32 + rs8]);           \
  } while (0)

#define MFMA8(a0, a1, bf, mi0)                                        \
  do {                                                                \
    __builtin_amdgcn_s_setprio(1);                                    \
    _Pragma("unroll")                                                 \
    for (int ni = 0; ni < 4; ++ni)                                    \
      acc[mi0][ni] = __builtin_amdgcn_mfma_f32_16x16x32_f16(          \
          a0, bf[ni], acc[mi0][ni], 0, 0, 0);                         \
    _Pragma("unroll")                                                 \
    for (int ni = 0; ni < 4; ++ni)                                    \
      acc[(mi0) + 1][ni] = __builtin_amdgcn_mfma_f32_16x16x32_f16(    \
          a1, bf[ni], acc[(mi0) + 1][ni], 0, 0, 0);                   \
    __builtin_amdgcn_s_setprio(0);                                    \
  } while (0)

#define WAIT_LGKM_FENCE()                                             \
  do {                                                                \
    asm volatile("s_waitcnt lgkmcnt(0)" ::: "memory");                \
    __builtin_amdgcn_sched_barrier(0);                                \
  } while (0)

  // prologue: stage(0), stage(1); drain stage(0) (vmcnt: 6 out -> keep 3)
  STAGE_A(0, 0); STAGE_B(0, 0);
  STAGE_A(1, 1); STAGE_B(1, 1);
  asm volatile("s_waitcnt vmcnt(3)" ::: "memory");
  __builtin_amdgcn_s_barrier();

  const int nk = CD / 32;  // 20
  f16x8 a0, a1, a2, a3, bf[4];
  for (int t = 0; t < nk - 2; ++t) {
    const int cur = t % 3, nxt = (t + 2) % 3;
    // ---- phase 1: reads + A-stage issue, then 8 MFMA (mi 0,1) ----
    READ_A2(a0, a1, cur, 0);
    READ_B4(bf, cur);
    STAGE_A(nxt, t + 2);
    __builtin_amdgcn_s_barrier();
    WAIT_LGKM_FENCE();
    MFMA8(a0, a1, bf, 0);
    __builtin_amdgcn_s_barrier();
    // ---- phase 2: reads + B-stage issue + boundary vmcnt, 8 MFMA (mi 2,3) --
    READ_A2(a2, a3, cur, 2);
    STAGE_B(nxt, t + 2);
    asm volatile("s_waitcnt vmcnt(3)" ::: "memory");   // stage(t+1) arrived
    __builtin_amdgcn_s_barrier();
    WAIT_LGKM_FENCE();
    MFMA8(a2, a3, bf, 2);
    __builtin_amdgcn_s_barrier();
  }
  // t = nk-2: no issue; drain stage(nk-1)
  {
    const int cur = (nk - 2) % 3;
    READ_A2(a0, a1, cur, 0);
    READ_B4(bf, cur);
    __builtin_amdgcn_s_barrier();
    WAIT_LGKM_FENCE();
    MFMA8(a0, a1, bf, 0);
    __builtin_amdgcn_s_barrier();
    READ_A2(a2, a3, cur, 2);
    asm volatile("s_waitcnt vmcnt(0)" ::: "memory");
    __builtin_amdgcn_s_barrier();
    WAIT_LGKM_FENCE();
    MFMA8(a2, a3, bf, 2);
    __builtin_amdgcn_s_barrier();
  }
  // t = nk-1: compute only
  {
    const int cur = (nk - 1) % 3;
    READ_A2(a0, a1, cur, 0);
    READ_B4(bf, cur);
    WAIT_LGKM_FENCE();
    MFMA8(a0, a1, bf, 0);
    READ_A2(a2, a3, cur, 2);
    WAIT_LGKM_FENCE();
    MFMA8(a2, a3, bf, 2);
  }

  if (EPI == 0) {
    half_t* O = (half_t*)outp;
#pragma unroll
    for (int ni = 0; ni < 4; ++ni) {
      const int n = n0 + wn * 64 + ni * 16 + ln;
      const float bvv = bias[n];
#pragma unroll
      for (int mi = 0; mi < 4; ++mi) {
        const long m = m0 + wm * 64 + mi * 16 + g * 4;
        f32x4 v = acc[mi][ni];
#pragma unroll
        for (int r = 0; r < 4; ++r)
          O[(m + r) * CD + n] = (half_t)(v[r] + bvv);
      }
    }
  } else {
    float* O = (float*)outp;
#pragma unroll
    for (int mi = 0; mi < 4; ++mi) {
      const long m = m0 + wm * 64 + mi * 16 + g * 4;
      const long bb = m >> 12;
      const int p = (int)(m & 4095);
#pragma unroll
      for (int ni = 0; ni < 4; ++ni) {
        const int n = n0 + wn * 64 + ni * 16 + ln;
        const float bvv = bias[n];
        f32x4 v = acc[mi][ni];
        float4 o4 = make_float4(v[0] + bvv, v[1] + bvv, v[2] + bvv, v[3] + bvv);
        *reinterpret_cast<float4*>(&O[((bb * CD + n) << 12) + p]) = o4;
      }
    }
  }
#undef STAGE_A
#undef STAGE_B
#undef READ_A2
#undef READ_B4
#undef MFMA8
#undef WAIT_LGKM_FENCE
}

// ---------------- fused attention (128 px / block, 512 threads) -------------
__global__ __launch_bounds__(512) void attn_kernel(
    const half_t* __restrict__ q_ws, const half_t* __restrict__ k_ws,
    const half_t* __restrict__ vT_ws, half_t* __restrict__ attn_ws) {
  __shared__ half_t K_sm[80][DP];
  __shared__ half_t V_sm[80][DP];
  __shared__ half_t Q_sm[128][DP];  // becomes P after softmax (pads stay 0)
  const int p0 = blockIdx.x * 128;
  const int h  = blockIdx.y;
  const int b  = blockIdx.z;
  const int tid = threadIdx.x, wave = tid >> 6, lane = tid & 63;
  const int g = lane >> 4, ln = lane & 15;

  const half_t* kp = k_ws  + ((long)b * NH + h) * 80 * DP;
  const half_t* vp = vT_ws + ((long)b * NH + h) * 80 * DP;
  for (int i = tid; i < 960; i += 512) {   // 80*96/8 int4 chunks
    reinterpret_cast<int4*>(K_sm)[i] = reinterpret_cast<const int4*>(kp)[i];
    reinterpret_cast<int4*>(V_sm)[i] = reinterpret_cast<const int4*>(vp)[i];
  }
  for (int i = tid; i < 1536; i += 512) {  // 128 rows x 12 chunks
    const int r = i / 12, c8 = i % 12;
    int4 v = make_int4(0, 0, 0, 0);
    if (c8 < 10)
      v = *reinterpret_cast<const int4*>(
          q_ws + ((long)(b * HWD + p0 + r)) * CD + h * DH + c8 * 8);
    *reinterpret_cast<int4*>(&Q_sm[r][c8 * 8]) = v;
  }
  __syncthreads();

  // S^T = K(80x96) @ Q^T(96x16)
  f32x4 s[5];
#pragma unroll
  for (int i = 0; i < 5; ++i) s[i] = (f32x4){0.f, 0.f, 0.f, 0.f};
#pragma unroll
  for (int ks = 0; ks < 3; ++ks) {
    f16x8 bq = *reinterpret_cast<const f16x8*>(&Q_sm[wave * 16 + ln][ks * 32 + g * 8]);
#pragma unroll
    for (int mt = 0; mt < 5; ++mt) {
      f16x8 ak = *reinterpret_cast<const f16x8*>(&K_sm[mt * 16 + ln][ks * 32 + g * 8]);
      s[mt] = __builtin_amdgcn_mfma_f32_16x16x32_f16(ak, bq, s[mt], 0, 0, 0);
    }
  }

  // masked softmax over t (valid t<77)
  const float sc = 0.11180339887498949f;   // 80^-0.5
  float mx = -1e30f;
#pragma unroll
  for (int mt = 0; mt < 5; ++mt)
#pragma unroll
    for (int r = 0; r < 4; ++r) {
      const int t = mt * 16 + g * 4 + r;
      const float v = s[mt][r] * sc;
      s[mt][r] = v;
      if (t < TT) mx = fmaxf(mx, v);
    }
  mx = fmaxf(mx, __shfl_xor(mx, 16));
  mx = fmaxf(mx, __shfl_xor(mx, 32));
  float e[5][4];
  float sum = 0.f;
#pragma unroll
  for (int mt = 0; mt < 5; ++mt)
#pragma unroll
    for (int r = 0; r < 4; ++r) {
      const int t = mt * 16 + g * 4 + r;
      float ev = 0.f;
      if (t < TT) { ev = __expf(s[mt][r] - mx); sum += ev; }
      e[mt][r] = ev;
    }
  sum += __shfl_xor(sum, 16);
  sum += __shfl_xor(sum, 32);
  const float inv = 1.f / sum;
#pragma unroll
  for (int mt = 0; mt < 5; ++mt) {
    f16x4 pv;
#pragma unroll
    for (int r = 0; r < 4; ++r) pv[r] = (half_t)(e[mt][r] * inv);
    *reinterpret_cast<f16x4*>(&Q_sm[wave * 16 + ln][mt * 16 + g * 4]) = pv;
  }

  // O^T = V^T(80x96) @ P(96x16)
  f32x4 o[5];
#pragma unroll
  for (int i = 0; i < 5; ++i) o[i] = (f32x4){0.f, 0.f, 0.f, 0.f};
#pragma unroll
  for (int ks = 0; ks < 3; ++ks) {
    f16x8 bp = *reinterpret_cast<const f16x8*>(&Q_sm[wave * 16 + ln][ks * 32 + g * 8]);
#pragma unroll
    for (int mt = 0; mt < 5; ++mt) {
      f16x8 av = *reinterpret_cast<const f16x8*>(&V_sm[mt * 16 + ln][ks * 32 + g * 8]);
      o[mt] = __builtin_amdgcn_mfma_f32_16x16x32_f16(av, bp, o[mt], 0, 0, 0);
    }
  }

  half_t* op = attn_ws + ((long)(b * HWD + p0 + wave * 16 + ln)) * CD + h * DH;
#pragma unroll
  for (int mt = 0; mt < 5; ++mt) {
    f16x4 v4;
#pragma unroll
    for (int r = 0; r < 4; ++r) v4[r] = (half_t)o[mt][r];
    *reinterpret_cast<f16x4*>(&op[mt * 16 + g * 4]) = v4;
  }
}

// ---------------- launch ----------------
extern "C" void kernel_launch(void* const* d_in, const int* in_sizes, int n_in,
                              void* d_out, int out_size, void* d_ws, size_t ws_size,
                              hipStream_t stream) {
  const float* x   = (const float*)d_in[0];
  const float* ctx = (const float*)d_in[1];
  const float* Wq  = (const float*)d_in[2];
  const float* bq  = (const float*)d_in[3];
  const float* Wk  = (const float*)d_in[4];
  const float* bk  = (const float*)d_in[5];
  const float* Wv  = (const float*)d_in[6];
  const float* bv  = (const float*)d_in[7];
  const float* Wo  = (const float*)d_in[8];
  const float* bo  = (const float*)d_in[9];
  float* out = (float*)d_out;

  char* ws = (char*)d_ws;
  size_t off = 0;
  auto alloc = [&](size_t bytes) {
    void* p = ws + off;
    off += (bytes + 255) & ~(size_t)255;
    return p;
  };
  half_t* WqT  = (half_t*)alloc((size_t)CD * CD * 2);
  half_t* WkT  = (half_t*)alloc((size_t)CD * CTXD * 2);
  half_t* WvT  = (half_t*)alloc((size_t)CD * CTXD * 2);
  half_t* WoT  = (half_t*)alloc((size_t)CD * CD * 2);
  half_t* kws  = (half_t*)alloc((size_t)NB * NH * 80 * DP * 2);
  half_t* vTws = (half_t*)alloc((size_t)NB * NH * 80 * DP * 2);
  half_t* xt   = (half_t*)alloc((size_t)NB * HWD * CD * 2);
  half_t* q    = (half_t*)alloc((size_t)NB * HWD * CD * 2);
  half_t* attn = xt;   // xt dead after pgemm8<0>; alias

  // zero padded K / V^T (contiguous pair)
  hipMemsetAsync(kws, 0, (size_t)2 * NB * NH * 80 * DP * 2, stream);

  // weight transposes (f32 -> f16)
  wtrans_kernel<<<dim3(CD / 64, CTXD / 64, 4), 256, 0, stream>>>(
      Wq, Wk, Wv, Wo, WqT, WkT, WvT, WoT);

  // K/V projection
  kv_kernel<<<dim3(CD / 64, NB, 2), 256, 0, stream>>>(ctx, WkT, WvT, bk, bv, kws, vTws);

  // x transpose + convert
  xpose_kernel<<<dim3(HWD / 64, CD / 64, NB), 256, 0, stream>>>(x, xt);

  // Q projection (256x128 tiles, phase-split schedule)
  pgemm8_kernel<0><<<(CD / 128) * ((NB * HWD) / 256), 512, 0, stream>>>(
      xt, WqT, bq, q);

  // fused attention (128 px / block)
  attn_kernel<<<dim3(HWD / 128, NH, NB), 512, 0, stream>>>(q, kws, vTws, attn);

  // O projection (256x128 tiles, phase-split schedule)
  pgemm8_kernel<1><<<(CD / 128) * ((NB * HWD) / 256), 512, 0, stream>>>(
      attn, WoT, bo, out);
}

// Round 6
// 305.927 us; speedup vs baseline: 1.0535x; 1.0170x over previous
//
#include <hip/hip_runtime.h>
#include <hip/hip_fp16.h>

typedef _Float16 half_t;
typedef _Float16 f16x8 __attribute__((ext_vector_type(8)));
typedef _Float16 f16x4 __attribute__((ext_vector_type(4)));
typedef float f32x4 __attribute__((ext_vector_type(4)));

// problem constants
#define NB   16
#define CD   640
#define HWD  4096
#define TT   77
#define CTXD 768
#define NH   8
#define DH   80
#define DP   96   // padded d / padded T for the attention kernel

#define GLOAD16(gp, lp)                                                        \
  __builtin_amdgcn_global_load_lds(                                            \
      (const __attribute__((address_space(1))) void*)(gp),                     \
      (__attribute__((address_space(3))) void*)(lp), 16, 0, 0)

// XCD-locality swizzle: 5 n-blocks of one 256-row m-panel -> same XCD.
// grid = 1280 = 8 XCD * 160 slots; 256 panels (%8==0) -> bijective.
__device__ inline void xcd_panel_map(int j, int& panel, int& nblk) {
  const int xcd = j & 7, slot = j >> 3;
  panel = (slot / 5) * 8 + xcd;
  nblk = slot % 5;
}

// ---------------- x transpose + f32->f16 convert ----------------
// x (B, 640, 4096) f32 -> xt (B, 4096, 640) f16
__global__ __launch_bounds__(256) void xpose_kernel(
    const float* __restrict__ x, half_t* __restrict__ xt) {
  __shared__ half_t tile[64][72];
  const float* s = x + (long)blockIdx.z * CD * HWD;
  half_t* d = xt + (long)blockIdx.z * HWD * CD;
  const int r0 = blockIdx.y * 64;   // channel
  const int c0 = blockIdx.x * 64;   // pixel
  const int t = threadIdx.x;
  const int rr = t >> 4, cc = (t & 15) * 4;
#pragma unroll
  for (int j = 0; j < 4; ++j) {
    const int r = rr + j * 16;
    float4 v = *reinterpret_cast<const float4*>(&s[(long)(r0 + r) * HWD + c0 + cc]);
    tile[cc + 0][r] = (half_t)v.x;
    tile[cc + 1][r] = (half_t)v.y;
    tile[cc + 2][r] = (half_t)v.z;
    tile[cc + 3][r] = (half_t)v.w;
  }
  __syncthreads();
  const int cr = t >> 2, rc = (t & 3) * 16;
  half_t* dp = &d[(long)(c0 + cr) * CD + r0 + rc];
  *reinterpret_cast<int4*>(dp)     = *reinterpret_cast<const int4*>(&tile[cr][rc]);
  *reinterpret_cast<int4*>(dp + 8) = *reinterpret_cast<const int4*>(&tile[cr][rc + 8]);
}

// ---------------- merged weight transpose + f32->f16 convert ----------------
__global__ __launch_bounds__(256) void wtrans_kernel(
    const float* __restrict__ Wq, const float* __restrict__ Wk,
    const float* __restrict__ Wv, const float* __restrict__ Wo,
    half_t* __restrict__ WqT, half_t* __restrict__ WkT,
    half_t* __restrict__ WvT, half_t* __restrict__ WoT) {
  __shared__ half_t tile[64][72];
  const int z = blockIdx.z;
  const float* src = (z == 0) ? Wq : (z == 1) ? Wk : (z == 2) ? Wv : Wo;
  half_t* dst      = (z == 0) ? WqT : (z == 1) ? WkT : (z == 2) ? WvT : WoT;
  const int R = (z == 1 || z == 2) ? CTXD : CD;
  const int r0 = blockIdx.y * 64, c0 = blockIdx.x * 64;
  if (r0 >= R) return;
  const int t = threadIdx.x;
  const int rr = t >> 4, cc = (t & 15) * 4;
#pragma unroll
  for (int j = 0; j < 4; ++j) {
    const int r = rr + j * 16;
    float4 v = *reinterpret_cast<const float4*>(&src[(long)(r0 + r) * CD + c0 + cc]);
    tile[cc + 0][r] = (half_t)v.x;
    tile[cc + 1][r] = (half_t)v.y;
    tile[cc + 2][r] = (half_t)v.z;
    tile[cc + 3][r] = (half_t)v.w;
  }
  __syncthreads();
  const int cr = t >> 2, rc = (t & 3) * 16;
  half_t* dp = &dst[(long)(c0 + cr) * R + r0 + rc];
  *reinterpret_cast<int4*>(dp)     = *reinterpret_cast<const int4*>(&tile[cr][rc]);
  *reinterpret_cast<int4*>(dp + 8) = *reinterpret_cast<const int4*>(&tile[cr][rc + 8]);
}

// ---------------- K/V projection ----------------
// ctx (B,77,768) f32 @ WT(640,768)^T + bias ->
//   kv==0: k_ws  (B, 8, 80, 96)  [t][dd]
//   kv==1: vT_ws (B, 8, 80, 96)  [dd][t]
// Pad columns [80,96) of each row are zeroed HERE (block x==0 of each
// (b,kv)) — replaces the host-side hipMemsetAsync. Pads only need to be
// finite (they multiply provably-zero Q/P columns in attn), but workspace
// poison may be NaN, so explicit zeroing is required.
__global__ __launch_bounds__(256) void kv_kernel(
    const float* __restrict__ ctx,
    const half_t* __restrict__ WkT, const half_t* __restrict__ WvT,
    const float* __restrict__ bk, const float* __restrict__ bv,
    half_t* __restrict__ k_ws, half_t* __restrict__ vT_ws) {
  __shared__ half_t C_sm[80][32];
  const int n0 = blockIdx.x * 64;
  const int b  = blockIdx.y;
  const int kv = blockIdx.z;
  const half_t* WT  = kv ? WvT : WkT;
  const float* bias = kv ? bv : bk;
  const int tid = threadIdx.x;
  const int wave = tid >> 6, lane = tid & 63, g = lane >> 4, ln = lane & 15;

  // zero the pad stripes (one block per (b,kv) covers all 8 heads):
  // rows r of [(b,h) x 80] each get cols [80,96) = 2 int4 zeroed.
  if (blockIdx.x == 0) {
    half_t* dst = kv ? vT_ws : k_ws;
    for (int i = tid; i < 1280; i += 256) {   // 8h * 80rows * 2 chunks
      const int hh = i / 160, rr = i % 160;   // row = rr>>1, chunk = rr&1
      half_t* p = dst + (((long)b * NH + hh) * 80 + (rr >> 1)) * DP + 80 + (rr & 1) * 8;
      *reinterpret_cast<int4*>(p) = make_int4(0, 0, 0, 0);
    }
  }

  f32x4 acc[5];
#pragma unroll
  for (int i = 0; i < 5; ++i) acc[i] = (f32x4){0.f, 0.f, 0.f, 0.f};

  for (int k0 = 0; k0 < CTXD; k0 += 32) {
    if (k0) __syncthreads();
    for (int i = tid; i < 320; i += 256) {
      const int r = i >> 2, c8 = (i & 3) * 8;
      f16x8 hv = {0, 0, 0, 0, 0, 0, 0, 0};
      if (r < TT) {
        const float* cp = ctx + ((long)b * TT + r) * CTXD + k0 + c8;
        float4 c0v = *reinterpret_cast<const float4*>(cp);
        float4 c1v = *reinterpret_cast<const float4*>(cp + 4);
        hv[0] = (half_t)c0v.x; hv[1] = (half_t)c0v.y;
        hv[2] = (half_t)c0v.z; hv[3] = (half_t)c0v.w;
        hv[4] = (half_t)c1v.x; hv[5] = (half_t)c1v.y;
        hv[6] = (half_t)c1v.z; hv[7] = (half_t)c1v.w;
      }
      *reinterpret_cast<f16x8*>(&C_sm[r][c8]) = hv;
    }
    __syncthreads();
    f16x8 bfr = *reinterpret_cast<const f16x8*>(
        &WT[(long)(n0 + wave * 16 + ln) * CTXD + k0 + g * 8]);
#pragma unroll
    for (int mt = 0; mt < 5; ++mt) {
      f16x8 afr = *reinterpret_cast<const f16x8*>(&C_sm[mt * 16 + ln][g * 8]);
      acc[mt] = __builtin_amdgcn_mfma_f32_16x16x32_f16(afr, bfr, acc[mt], 0, 0, 0);
    }
  }

  const int n = n0 + wave * 16 + ln;
  const float bsv = bias[n];
  const int h = n / DH, dd = n % DH;
  if (kv == 0) {
#pragma unroll
    for (int mt = 0; mt < 5; ++mt)
#pragma unroll
      for (int r = 0; r < 4; ++r) {
        const int t = mt * 16 + g * 4 + r;
        k_ws[(((long)b * NH + h) * 80 + t) * DP + dd] = (half_t)(acc[mt][r] + bsv);
      }
  } else {
#pragma unroll
    for (int mt = 0; mt < 5; ++mt) {
      const int t0 = mt * 16 + g * 4;
      f16x4 v4;
#pragma unroll
      for (int r = 0; r < 4; ++r) v4[r] = (half_t)(acc[mt][r] + bsv);
      *reinterpret_cast<f16x4*>(&vT_ws[(((long)b * NH + h) * 80 + dd) * DP + t0]) = v4;
    }
  }
}

// ---------------- panel GEMM, 256x128 tile, PHASE-SPLIT schedule ------------
// Each BK=32 step: 2 phases of 8 MFMA (T3), counted vmcnt(3) once per step
// (T4, never 0 in main loop), triple buffer, setprio around MFMA (T5).
// Measured round 5: 96 us, MfmaUtil 23, conflicts 0.
template <int EPI>
__global__ __launch_bounds__(512, 4) void pgemm8_kernel(
    const half_t* __restrict__ A, const half_t* __restrict__ BT,
    const float* __restrict__ bias, void* __restrict__ outp) {
  __shared__ __align__(16) half_t A_sm[3][256 * 32];   // 48 KB
  __shared__ __align__(16) half_t B_sm[3][128 * 32];   // 24 KB
  const int tid = threadIdx.x;
  const int lane = tid & 63, wave = tid >> 6;   // wave 0..7
  const int g = lane >> 4, ln = lane & 15;
  const int wm = wave >> 1, wn = wave & 1;      // 4 x 2 wave grid

  int panel, nblk;
  xcd_panel_map(blockIdx.x, panel, nblk);
  const long m0 = (long)panel * 256;
  const int n0 = nblk * 128;

  // staging: lane l -> row wave*16+(l>>2), phys slot l&3 holds source
  // k-chunk (l&3)^((l>>3)&3)  [proven 0-conflict, rounds 0-5]
  const int srow = tid >> 2;                                  // 0..127
  const int sk8 = ((tid & 3) ^ ((tid >> 3) & 3)) * 8;
  const half_t* ag0 = A + (m0 + srow) * CD + sk8;
  const half_t* ag1 = ag0 + 128 * CD;                         // rows 128..255
  const half_t* bg0 = BT + (long)(n0 + srow) * CD + sk8;

  // fragment-read slot (loop-invariant): g ^ ((ln>>1)&3)
  const int rs8 = (g ^ ((ln >> 1) & 3)) * 8;

  f32x4 acc[4][4];
#pragma unroll
  for (int i = 0; i < 4; ++i)
#pragma unroll
    for (int j = 0; j < 4; ++j) acc[i][j] = (f32x4){0.f, 0.f, 0.f, 0.f};

#define STAGE_A(buf, kt)                                              \
  do {                                                                \
    GLOAD16(ag0 + (long)(kt) * 32, &A_sm[buf][wave * 512]);           \
    GLOAD16(ag1 + (long)(kt) * 32, &A_sm[buf][4096 + wave * 512]);    \
  } while (0)
#define STAGE_B(buf, kt)                                              \
  GLOAD16(bg0 + (long)(kt) * 32, &B_sm[buf][wave * 512])

#define READ_A2(dst0, dst1, buf, mi0)                                 \
  do {                                                                \
    dst0 = *reinterpret_cast<const f16x8*>(                           \
        &A_sm[buf][(wm * 64 + (mi0) * 16 + ln) * 32 + rs8]);          \
    dst1 = *reinterpret_cast<const f16x8*>(                           \
        &A_sm[buf][(wm * 64 + ((mi0) + 1) * 16 + ln) * 32 + rs8]);    \
  } while (0)
#define READ_B4(bf, buf)                                              \
  do {                                                                \
    _Pragma("unroll")                                                 \
    for (int ni = 0; ni < 4; ++ni)                                    \
      bf[ni] = *reinterpret_cast<const f16x8*>(                       \
          &B_sm[buf][(wn * 64 + ni * 16 + ln) * 32 + rs8]);           \
  } while (0)

#define MFMA8(a0, a1, bf, mi0)                                        \
  do {                                                                \
    __builtin_amdgcn_s_setprio(1);                                    \
    _Pragma("unroll")                                                 \
    for (int ni = 0; ni < 4; ++ni)                                    \
      acc[mi0][ni] = __builtin_amdgcn_mfma_f32_16x16x32_f16(          \
          a0, bf[ni], acc[mi0][ni], 0, 0, 0);                         \
    _Pragma("unroll")                                                 \
    for (int ni = 0; ni < 4; ++ni)                                    \
      acc[(mi0) + 1][ni] = __builtin_amdgcn_mfma_f32_16x16x32_f16(    \
          a1, bf[ni], acc[(mi0) + 1][ni], 0, 0, 0);                   \
    __builtin_amdgcn_s_setprio(0);                                    \
  } while (0)

#define WAIT_LGKM_FENCE()                                             \
  do {                                                                \
    asm volatile("s_waitcnt lgkmcnt(0)" ::: "memory");                \
    __builtin_amdgcn_sched_barrier(0);                                \
  } while (0)

  // prologue: stage(0), stage(1); drain stage(0) (vmcnt: 6 out -> keep 3)
  STAGE_A(0, 0); STAGE_B(0, 0);
  STAGE_A(1, 1); STAGE_B(1, 1);
  asm volatile("s_waitcnt vmcnt(3)" ::: "memory");
  __builtin_amdgcn_s_barrier();

  const int nk = CD / 32;  // 20
  f16x8 a0, a1, a2, a3, bf[4];
  for (int t = 0; t < nk - 2; ++t) {
    const int cur = t % 3, nxt = (t + 2) % 3;
    // ---- phase 1: reads + A-stage issue, then 8 MFMA (mi 0,1) ----
    READ_A2(a0, a1, cur, 0);
    READ_B4(bf, cur);
    STAGE_A(nxt, t + 2);
    __builtin_amdgcn_s_barrier();
    WAIT_LGKM_FENCE();
    MFMA8(a0, a1, bf, 0);
    __builtin_amdgcn_s_barrier();
    // ---- phase 2: reads + B-stage issue + boundary vmcnt, 8 MFMA (mi 2,3) --
    READ_A2(a2, a3, cur, 2);
    STAGE_B(nxt, t + 2);
    asm volatile("s_waitcnt vmcnt(3)" ::: "memory");   // stage(t+1) arrived
    __builtin_amdgcn_s_barrier();
    WAIT_LGKM_FENCE();
    MFMA8(a2, a3, bf, 2);
    __builtin_amdgcn_s_barrier();
  }
  // t = nk-2: no issue; drain stage(nk-1)
  {
    const int cur = (nk - 2) % 3;
    READ_A2(a0, a1, cur, 0);
    READ_B4(bf, cur);
    __builtin_amdgcn_s_barrier();
    WAIT_LGKM_FENCE();
    MFMA8(a0, a1, bf, 0);
    __builtin_amdgcn_s_barrier();
    READ_A2(a2, a3, cur, 2);
    asm volatile("s_waitcnt vmcnt(0)" ::: "memory");
    __builtin_amdgcn_s_barrier();
    WAIT_LGKM_FENCE();
    MFMA8(a2, a3, bf, 2);
    __builtin_amdgcn_s_barrier();
  }
  // t = nk-1: compute only
  {
    const int cur = (nk - 1) % 3;
    READ_A2(a0, a1, cur, 0);
    READ_B4(bf, cur);
    WAIT_LGKM_FENCE();
    MFMA8(a0, a1, bf, 0);
    READ_A2(a2, a3, cur, 2);
    WAIT_LGKM_FENCE();
    MFMA8(a2, a3, bf, 2);
  }

  if (EPI == 0) {
    half_t* O = (half_t*)outp;
#pragma unroll
    for (int ni = 0; ni < 4; ++ni) {
      const int n = n0 + wn * 64 + ni * 16 + ln;
      const float bvv = bias[n];
#pragma unroll
      for (int mi = 0; mi < 4; ++mi) {
        const long m = m0 + wm * 64 + mi * 16 + g * 4;
        f32x4 v = acc[mi][ni];
#pragma unroll
        for (int r = 0; r < 4; ++r)
          O[(m + r) * CD + n] = (half_t)(v[r] + bvv);
      }
    }
  } else {
    float* O = (float*)outp;
#pragma unroll
    for (int mi = 0; mi < 4; ++mi) {
      const long m = m0 + wm * 64 + mi * 16 + g * 4;
      const long bb = m >> 12;
      const int p = (int)(m & 4095);
#pragma unroll
      for (int ni = 0; ni < 4; ++ni) {
        const int n = n0 + wn * 64 + ni * 16 + ln;
        const float bvv = bias[n];
        f32x4 v = acc[mi][ni];
        float4 o4 = make_float4(v[0] + bvv, v[1] + bvv, v[2] + bvv, v[3] + bvv);
        *reinterpret_cast<float4*>(&O[((bb * CD + n) << 12) + p]) = o4;
      }
    }
  }
#undef STAGE_A
#undef STAGE_B
#undef READ_A2
#undef READ_B4
#undef MFMA8
#undef WAIT_LGKM_FENCE
}

// ---------------- fused attention (128 px / block, 512 threads) -------------
__global__ __launch_bounds__(512) void attn_kernel(
    const half_t* __restrict__ q_ws, const half_t* __restrict__ k_ws,
    const half_t* __restrict__ vT_ws, half_t* __restrict__ attn_ws) {
  __shared__ half_t K_sm[80][DP];
  __shared__ half_t V_sm[80][DP];
  __shared__ half_t Q_sm[128][DP];  // becomes P after softmax (pads stay 0)
  const int p0 = blockIdx.x * 128;
  const int h  = blockIdx.y;
  const int b  = blockIdx.z;
  const int tid = threadIdx.x, wave = tid >> 6, lane = tid & 63;
  const int g = lane >> 4, ln = lane & 15;

  const half_t* kp = k_ws  + ((long)b * NH + h) * 80 * DP;
  const half_t* vp = vT_ws + ((long)b * NH + h) * 80 * DP;
  for (int i = tid; i < 960; i += 512) {   // 80*96/8 int4 chunks
    reinterpret_cast<int4*>(K_sm)[i] = reinterpret_cast<const int4*>(kp)[i];
    reinterpret_cast<int4*>(V_sm)[i] = reinterpret_cast<const int4*>(vp)[i];
  }
  for (int i = tid; i < 1536; i += 512) {  // 128 rows x 12 chunks
    const int r = i / 12, c8 = i % 12;
    int4 v = make_int4(0, 0, 0, 0);
    if (c8 < 10)
      v = *reinterpret_cast<const int4*>(
          q_ws + ((long)(b * HWD + p0 + r)) * CD + h * DH + c8 * 8);
    *reinterpret_cast<int4*>(&Q_sm[r][c8 * 8]) = v;
  }
  __syncthreads();

  // S^T = K(80x96) @ Q^T(96x16)
  f32x4 s[5];
#pragma unroll
  for (int i = 0; i < 5; ++i) s[i] = (f32x4){0.f, 0.f, 0.f, 0.f};
#pragma unroll
  for (int ks = 0; ks < 3; ++ks) {
    f16x8 bq = *reinterpret_cast<const f16x8*>(&Q_sm[wave * 16 + ln][ks * 32 + g * 8]);
#pragma unroll
    for (int mt = 0; mt < 5; ++mt) {
      f16x8 ak = *reinterpret_cast<const f16x8*>(&K_sm[mt * 16 + ln][ks * 32 + g * 8]);
      s[mt] = __builtin_amdgcn_mfma_f32_16x16x32_f16(ak, bq, s[mt], 0, 0, 0);
    }
  }

  // masked softmax over t (valid t<77)
  const float sc = 0.11180339887498949f;   // 80^-0.5
  float mx = -1e30f;
#pragma unroll
  for (int mt = 0; mt < 5; ++mt)
#pragma unroll
    for (int r = 0; r < 4; ++r) {
      const int t = mt * 16 + g * 4 + r;
      const float v = s[mt][r] * sc;
      s[mt][r] = v;
      if (t < TT) mx = fmaxf(mx, v);
    }
  mx = fmaxf(mx, __shfl_xor(mx, 16));
  mx = fmaxf(mx, __shfl_xor(mx, 32));
  float e[5][4];
  float sum = 0.f;
#pragma unroll
  for (int mt = 0; mt < 5; ++mt)
#pragma unroll
    for (int r = 0; r < 4; ++r) {
      const int t = mt * 16 + g * 4 + r;
      float ev = 0.f;
      if (t < TT) { ev = __expf(s[mt][r] - mx); sum += ev; }
      e[mt][r] = ev;
    }
  sum += __shfl_xor(sum, 16);
  sum += __shfl_xor(sum, 32);
  const float inv = 1.f / sum;
#pragma unroll
  for (int mt = 0; mt < 5; ++mt) {
    f16x4 pv;
#pragma unroll
    for (int r = 0; r < 4; ++r) pv[r] = (half_t)(e[mt][r] * inv);
    *reinterpret_cast<f16x4*>(&Q_sm[wave * 16 + ln][mt * 16 + g * 4]) = pv;
  }

  // O^T = V^T(80x96) @ P(96x16)
  f32x4 o[5];
#pragma unroll
  for (int i = 0; i < 5; ++i) o[i] = (f32x4){0.f, 0.f, 0.f, 0.f};
#pragma unroll
  for (int ks = 0; ks < 3; ++ks) {
    f16x8 bp = *reinterpret_cast<const f16x8*>(&Q_sm[wave * 16 + ln][ks * 32 + g * 8]);
#pragma unroll
    for (int mt = 0; mt < 5; ++mt) {
      f16x8 av = *reinterpret_cast<const f16x8*>(&V_sm[mt * 16 + ln][ks * 32 + g * 8]);
      o[mt] = __builtin_amdgcn_mfma_f32_16x16x32_f16(av, bp, o[mt], 0, 0, 0);
    }
  }

  half_t* op = attn_ws + ((long)(b * HWD + p0 + wave * 16 + ln)) * CD + h * DH;
#pragma unroll
  for (int mt = 0; mt < 5; ++mt) {
    f16x4 v4;
#pragma unroll
    for (int r = 0; r < 4; ++r) v4[r] = (half_t)o[mt][r];
    *reinterpret_cast<f16x4*>(&op[mt * 16 + g * 4]) = v4;
  }
}

// ---------------- launch ----------------
extern "C" void kernel_launch(void* const* d_in, const int* in_sizes, int n_in,
                              void* d_out, int out_size, void* d_ws, size_t ws_size,
                              hipStream_t stream) {
  const float* x   = (const float*)d_in[0];
  const float* ctx = (const float*)d_in[1];
  const float* Wq  = (const float*)d_in[2];
  const float* bq  = (const float*)d_in[3];
  const float* Wk  = (const float*)d_in[4];
  const float* bk  = (const float*)d_in[5];
  const float* Wv  = (const float*)d_in[6];
  const float* bv  = (const float*)d_in[7];
  const float* Wo  = (const float*)d_in[8];
  const float* bo  = (const float*)d_in[9];
  float* out = (float*)d_out;

  char* ws = (char*)d_ws;
  size_t off = 0;
  auto alloc = [&](size_t bytes) {
    void* p = ws + off;
    off += (bytes + 255) & ~(size_t)255;
    return p;
  };
  half_t* WqT  = (half_t*)alloc((size_t)CD * CD * 2);
  half_t* WkT  = (half_t*)alloc((size_t)CD * CTXD * 2);
  half_t* WvT  = (half_t*)alloc((size_t)CD * CTXD * 2);
  half_t* WoT  = (half_t*)alloc((size_t)CD * CD * 2);
  half_t* kws  = (half_t*)alloc((size_t)NB * NH * 80 * DP * 2);
  half_t* vTws = (half_t*)alloc((size_t)NB * NH * 80 * DP * 2);
  half_t* xt   = (half_t*)alloc((size_t)NB * HWD * CD * 2);
  half_t* q    = (half_t*)alloc((size_t)NB * HWD * CD * 2);
  half_t* attn = xt;   // xt dead after pgemm8<0>; alias

  // (memset removed: kv_kernel zeroes the pad stripes itself)

  // weight transposes (f32 -> f16)
  wtrans_kernel<<<dim3(CD / 64, CTXD / 64, 4), 256, 0, stream>>>(
      Wq, Wk, Wv, Wo, WqT, WkT, WvT, WoT);

  // K/V projection (+ pad zeroing)
  kv_kernel<<<dim3(CD / 64, NB, 2), 256, 0, stream>>>(ctx, WkT, WvT, bk, bv, kws, vTws);

  // x transpose + convert
  xpose_kernel<<<dim3(HWD / 64, CD / 64, NB), 256, 0, stream>>>(x, xt);

  // Q projection (256x128 tiles, phase-split schedule)
  pgemm8_kernel<0><<<(CD / 128) * ((NB * HWD) / 256), 512, 0, stream>>>(
      xt, WqT, bq, q);

  // fused attention (128 px / block)
  attn_kernel<<<dim3(HWD / 128, NH, NB), 512, 0, stream>>>(q, kws, vTws, attn);

  // O projection (256x128 tiles, phase-split schedule)
  pgemm8_kernel<1><<<(CD / 128) * ((NB * HWD) / 256), 512, 0, stream>>>(
      attn, WoT, bo, out);
}